// Round 1
// 3913.490 us; speedup vs baseline: 1.0355x; 1.0355x over previous
//
#include <hip/hip_runtime.h>

// QuantizedTokenizer: encoder MLP -> VQ argmin -> gather -> decoder MLP.
// B=32, Q=1024 -> N=32768 rows. H=1024, HR=512, C=4096.
// All-fp32 (argmin fidelity requires it; bf16 noise flips nearest-code picks).
//
// R1: eliminate 4-way LDS bank conflicts on B-fragment reads by splitting each
// thread's 8 columns into two float4 chunks at tx*4 and 64+tx*4 (2-way = free),
// float4 epilogue stores, and shfl-based argmin reduction (drops 16KB LDS +
// one barrier from dist_argmin -> 8 blocks/CU instead of 4).

#define BM 128
#define BN 128
#define BK 16
#define TM 8
#define TN 8

#define NROW 32768
#define HDIM 1024
#define HRDIM 512
#define CODES 4096

// ---------------------------------------------------------------------------
// Generic fp32 GEMM: C[M,N] = act(A[M,K] @ B[K,N] + bias[N])
// A,B,C row-major. M%128==0, N%128==0, K%16==0 (true for all our shapes).
// 256 threads, 8x8 per thread; columns split as [tx*4 .. +3] and [64+tx*4 .. +3].
// ---------------------------------------------------------------------------
__global__ __launch_bounds__(256) void sgemm_bias(
    const float* __restrict__ A, const float* __restrict__ B,
    const float* __restrict__ bias, float* __restrict__ C,
    int M, int N, int K, int do_relu)
{
    __shared__ __align__(16) float As[BK][BM + 4];
    __shared__ __align__(16) float Bs[BK][BN + 4];

    const int tid = threadIdx.x;
    const int tx = tid & 15;   // col group 0..15
    const int ty = tid >> 4;   // row group 0..15
    const int block_row = blockIdx.y * BM;
    const int block_col = blockIdx.x * BN;

    float acc[TM][TN] = {};

    // A tile loads: 128x16 floats = 512 float4, 2 per thread
    const int a_r0 = tid >> 2;          // 0..63
    const int a_c0 = (tid & 3) << 2;    // 0,4,8,12
    // B tile loads: 16x128 floats, 2 float4 per thread
    const int b_r0 = tid >> 5;          // 0..7
    const int b_c0 = (tid & 31) << 2;   // 0..124

    const float* Ab = A + (size_t)block_row * K;

    for (int k0 = 0; k0 < K; k0 += BK) {
#pragma unroll
        for (int i = 0; i < 2; ++i) {
            int r = a_r0 + i * 64;
            float4 v = *(const float4*)(Ab + (size_t)r * K + k0 + a_c0);
            As[a_c0 + 0][r] = v.x;
            As[a_c0 + 1][r] = v.y;
            As[a_c0 + 2][r] = v.z;
            As[a_c0 + 3][r] = v.w;
        }
#pragma unroll
        for (int i = 0; i < 2; ++i) {
            int r = b_r0 + i * 8;
            float4 v = *(const float4*)(B + (size_t)(k0 + r) * N + block_col + b_c0);
            *(float4*)(&Bs[r][b_c0]) = v;
        }
        __syncthreads();
#pragma unroll
        for (int k = 0; k < BK; ++k) {
            float4 a0 = *(const float4*)(&As[k][ty * 8]);
            float4 a1 = *(const float4*)(&As[k][ty * 8 + 4]);
            float4 b0 = *(const float4*)(&Bs[k][tx * 4]);        // 2-way, free
            float4 b1 = *(const float4*)(&Bs[k][tx * 4 + 64]);   // 2-way, free
            float am[TM] = {a0.x, a0.y, a0.z, a0.w, a1.x, a1.y, a1.z, a1.w};
            float bn[TN] = {b0.x, b0.y, b0.z, b0.w, b1.x, b1.y, b1.z, b1.w};
#pragma unroll
            for (int i = 0; i < TM; ++i)
#pragma unroll
                for (int j = 0; j < TN; ++j)
                    acc[i][j] = fmaf(am[i], bn[j], acc[i][j]);
        }
        __syncthreads();
    }

    // epilogue: two float4 stores per row
    float4 bv0 = *(const float4*)(bias + block_col + tx * 4);
    float4 bv1 = *(const float4*)(bias + block_col + 64 + tx * 4);
#pragma unroll
    for (int i = 0; i < TM; ++i) {
        int gr = block_row + ty * TM + i;
        float* Crow = C + (size_t)gr * N + block_col;
        float4 v0, v1;
        v0.x = acc[i][0] + bv0.x;  v0.y = acc[i][1] + bv0.y;
        v0.z = acc[i][2] + bv0.z;  v0.w = acc[i][3] + bv0.w;
        v1.x = acc[i][4] + bv1.x;  v1.y = acc[i][5] + bv1.y;
        v1.z = acc[i][6] + bv1.z;  v1.w = acc[i][7] + bv1.w;
        if (do_relu) {
            v0.x = fmaxf(v0.x, 0.0f); v0.y = fmaxf(v0.y, 0.0f);
            v0.z = fmaxf(v0.z, 0.0f); v0.w = fmaxf(v0.w, 0.0f);
            v1.x = fmaxf(v1.x, 0.0f); v1.y = fmaxf(v1.y, 0.0f);
            v1.z = fmaxf(v1.z, 0.0f); v1.w = fmaxf(v1.w, 0.0f);
        }
        *(float4*)(Crow + tx * 4) = v0;
        *(float4*)(Crow + 64 + tx * 4) = v1;
    }
}

// ---------------------------------------------------------------------------
// codebook row sumsq: cb2[c] = sum_k codebook[c][k]^2. One wave per row.
// ---------------------------------------------------------------------------
__global__ __launch_bounds__(256) void cb2_kernel(const float* __restrict__ CB,
                                                  float* __restrict__ cb2)
{
    int row = blockIdx.x * 4 + (threadIdx.x >> 6);
    int lane = threadIdx.x & 63;
    const float* cr = CB + (size_t)row * HRDIM;
    float s = 0.0f;
#pragma unroll
    for (int i = 0; i < 2; ++i) {
        int c = lane * 4 + i * 256;
        float4 v = *(const float4*)(cr + c);
        s = fmaf(v.x, v.x, s);
        s = fmaf(v.y, v.y, s);
        s = fmaf(v.z, v.z, s);
        s = fmaf(v.w, v.w, s);
    }
#pragma unroll
    for (int off = 32; off > 0; off >>= 1) s += __shfl_down(s, off, 64);
    if (lane == 0) cb2[row] = s;
}

// ---------------------------------------------------------------------------
// Distance GEMM + fused per-row argmin. d[n][c] = cb2[c] - 2*z_n.cb_c
// (same expansion as reference; z^2 term constant per row, skipped).
// Per-block 128x128 distance tile -> per-row packed (orderkey(d)<<32 | col)
// min -> shfl butterfly across the 16 tx lanes -> atomicMin into packed[row].
// Tie -> lowest col, matching np.argmin.
// ---------------------------------------------------------------------------
__device__ __forceinline__ unsigned int float_orderkey(float f)
{
    unsigned int u = __float_as_uint(f);
    return (u & 0x80000000u) ? ~u : (u | 0x80000000u);
}

__global__ __launch_bounds__(256) void dist_argmin(
    const float* __restrict__ Z, const float* __restrict__ CB,
    const float* __restrict__ cb2, unsigned long long* __restrict__ packed)
{
    __shared__ __align__(16) float As[BK][BM + 4];
    __shared__ __align__(16) float Bs[BK][BN + 4];

    const int tid = threadIdx.x;
    const int tx = tid & 15;
    const int ty = tid >> 4;
    const int block_row = blockIdx.y * BM;
    const int block_col = blockIdx.x * BN;
    const int K = HRDIM;

    float acc[TM][TN] = {};

    const int a_r0 = tid >> 2;        // 0..63
    const int a_c0 = (tid & 3) << 2;  // 0,4,8,12

    const float* Ab = Z + (size_t)block_row * K;

    for (int k0 = 0; k0 < K; k0 += BK) {
#pragma unroll
        for (int i = 0; i < 2; ++i) {
            int r = a_r0 + i * 64;
            float4 v = *(const float4*)(Ab + (size_t)r * K + k0 + a_c0);
            As[a_c0 + 0][r] = v.x;
            As[a_c0 + 1][r] = v.y;
            As[a_c0 + 2][r] = v.z;
            As[a_c0 + 3][r] = v.w;
        }
        // B tile = codebook^T: Bs[k][n] = CB[block_col+n][k0+k]
#pragma unroll
        for (int i = 0; i < 2; ++i) {
            int n = a_r0 + i * 64;
            float4 v = *(const float4*)(CB + (size_t)(block_col + n) * K + k0 + a_c0);
            Bs[a_c0 + 0][n] = v.x;
            Bs[a_c0 + 1][n] = v.y;
            Bs[a_c0 + 2][n] = v.z;
            Bs[a_c0 + 3][n] = v.w;
        }
        __syncthreads();
#pragma unroll
        for (int k = 0; k < BK; ++k) {
            float4 a0 = *(const float4*)(&As[k][ty * 8]);
            float4 a1 = *(const float4*)(&As[k][ty * 8 + 4]);
            float4 b0 = *(const float4*)(&Bs[k][tx * 4]);
            float4 b1 = *(const float4*)(&Bs[k][tx * 4 + 64]);
            float am[TM] = {a0.x, a0.y, a0.z, a0.w, a1.x, a1.y, a1.z, a1.w};
            float bn[TN] = {b0.x, b0.y, b0.z, b0.w, b1.x, b1.y, b1.z, b1.w};
#pragma unroll
            for (int i = 0; i < TM; ++i)
#pragma unroll
                for (int j = 0; j < TN; ++j)
                    acc[i][j] = fmaf(am[i], bn[j], acc[i][j]);
        }
        __syncthreads();
    }

    // per-thread min over its 8 columns (two 4-col chunks), then shfl
    // butterfly over the 16 tx lanes (lane bits 0..3), then one atomic/row.
    float4 c2a = *(const float4*)(cb2 + block_col + tx * 4);
    float4 c2b = *(const float4*)(cb2 + block_col + 64 + tx * 4);
    const float c2[TN] = {c2a.x, c2a.y, c2a.z, c2a.w, c2b.x, c2b.y, c2b.z, c2b.w};

#pragma unroll
    for (int i = 0; i < TM; ++i) {
        unsigned long long best = 0xFFFFFFFFFFFFFFFFull;
#pragma unroll
        for (int j = 0; j < TN; ++j) {
            int col = block_col + ((j < 4) ? (tx * 4 + j) : (64 + tx * 4 + j - 4));
            float d = c2[j] - 2.0f * acc[i][j];
            unsigned long long p =
                ((unsigned long long)float_orderkey(d) << 32) | (unsigned int)col;
            best = (p < best) ? p : best;
        }
#pragma unroll
        for (int m = 1; m < 16; m <<= 1) {
            unsigned long long o = __shfl_xor(best, m, 64);
            best = (o < best) ? o : best;
        }
        if (tx == 0)
            atomicMin(&packed[block_row + ty * TM + i], best);
    }
}

// ---------------------------------------------------------------------------
// Gather pass: one wave per row. Emits quantized rows, float(idx), and
// per-block commit partial: sum over rows of (||z||^2 + dmin) = ||z-q||^2.
// ---------------------------------------------------------------------------
__global__ __launch_bounds__(256) void gather_pass(
    const float* __restrict__ Z, const unsigned long long* __restrict__ packed,
    const float* __restrict__ CB, float* __restrict__ Q,
    float* __restrict__ IDX, float* __restrict__ partials)
{
    __shared__ float s[4];
    int row = blockIdx.x * 4 + (threadIdx.x >> 6);
    int lane = threadIdx.x & 63;

    unsigned long long p = packed[row];
    int idx = (int)(unsigned int)(p & 0xFFFFFFFFull);

    const float* zr = Z + (size_t)row * HRDIM;
    const float* cr = CB + (size_t)idx * HRDIM;
    float* qr = Q + (size_t)row * HRDIM;

    float z2 = 0.0f;
#pragma unroll
    for (int i = 0; i < 2; ++i) {
        int c = lane * 4 + i * 256;
        float4 zv = *(const float4*)(zr + c);
        float4 cv = *(const float4*)(cr + c);
        *(float4*)(qr + c) = cv;
        z2 = fmaf(zv.x, zv.x, z2);
        z2 = fmaf(zv.y, zv.y, z2);
        z2 = fmaf(zv.z, zv.z, z2);
        z2 = fmaf(zv.w, zv.w, z2);
    }
#pragma unroll
    for (int off = 32; off > 0; off >>= 1) z2 += __shfl_down(z2, off, 64);

    if (lane == 0) {
        unsigned int u = (unsigned int)(p >> 32);
        unsigned int bits = (u & 0x80000000u) ? (u ^ 0x80000000u) : ~u;
        float dmin = __uint_as_float(bits);
        IDX[row] = (float)idx;
        s[threadIdx.x >> 6] = z2 + dmin;   // == ||z - q||^2
    }
    __syncthreads();
    if (threadIdx.x == 0) partials[blockIdx.x] = s[0] + s[1] + s[2] + s[3];
}

__global__ __launch_bounds__(256) void commit_final(
    const float* __restrict__ partials, int n, float* __restrict__ outv)
{
    __shared__ float s[256];
    float v = 0.0f;
    for (int i = threadIdx.x; i < n; i += 256) v += partials[i];
    s[threadIdx.x] = v;
    __syncthreads();
    for (int st = 128; st > 0; st >>= 1) {
        if (threadIdx.x < st) s[threadIdx.x] += s[threadIdx.x + st];
        __syncthreads();
    }
    if (threadIdx.x == 0)
        outv[0] = 0.25f * s[0] / (float)(NROW * HRDIM);
}

// ---------------------------------------------------------------------------
extern "C" void kernel_launch(void* const* d_in, const int* in_sizes, int n_in,
                              void* d_out, int out_size, void* d_ws, size_t ws_size,
                              hipStream_t stream)
{
    const float* x   = (const float*)d_in[0];
    const float* ew1 = (const float*)d_in[1];
    const float* eb1 = (const float*)d_in[2];
    const float* ew2 = (const float*)d_in[3];
    const float* eb2 = (const float*)d_in[4];
    const float* cb  = (const float*)d_in[5];
    const float* dw1 = (const float*)d_in[6];
    const float* db1 = (const float*)d_in[7];
    const float* dw2 = (const float*)d_in[8];
    const float* db2 = (const float*)d_in[9];

    float* out   = (float*)d_out;
    float* recon = out;                              // 33554432 floats
    float* qst   = out + 33554432;                   // 16777216 floats
    float* idxf  = out + 33554432 + 16777216;        // 32768 floats
    float* loss  = out + 33554432 + 16777216 + 32768; // 1 float

    char* ws = (char*)d_ws;
    float* h = (float*)ws;                                   // 32768*1024 f32 = 128 MB
    unsigned long long* packed =
        (unsigned long long*)(ws + (size_t)134217728);       // 32768*8 = 256 KB
    float* cb2      = (float*)(ws + (size_t)134217728 + 262144);          // 16 KB
    float* partials = (float*)(ws + (size_t)134217728 + 262144 + 16384);  // 32 KB
    float* z = recon;  // z [32768,512] staged in recon segment (written last)

    hipMemsetAsync(packed, 0xFF, NROW * sizeof(unsigned long long), stream);
    cb2_kernel<<<CODES / 4, 256, 0, stream>>>(cb, cb2);

    // encoder
    sgemm_bias<<<dim3(HDIM / BN, NROW / BM), 256, 0, stream>>>(
        x, ew1, eb1, h, NROW, HDIM, HDIM, 1);
    sgemm_bias<<<dim3(HRDIM / BN, NROW / BM), 256, 0, stream>>>(
        h, ew2, eb2, z, NROW, HRDIM, HDIM, 0);

    // VQ
    dist_argmin<<<dim3(CODES / BN, NROW / BM), 256, 0, stream>>>(z, cb, cb2, packed);
    gather_pass<<<NROW / 4, 256, 0, stream>>>(z, packed, cb, qst, idxf, partials);

    // decoder (reads q from the output buffer; h reused for h2)
    sgemm_bias<<<dim3(HDIM / BN, NROW / BM), 256, 0, stream>>>(
        qst, dw1, db1, h, NROW, HDIM, HRDIM, 1);
    sgemm_bias<<<dim3(HDIM / BN, NROW / BM), 256, 0, stream>>>(
        h, dw2, db2, recon, NROW, HDIM, HDIM, 0);

    commit_final<<<1, 256, 0, stream>>>(partials, NROW / 4, loss);
}